// Round 4
// baseline (128.132 us; speedup 1.0000x reference)
//
#include <hip/hip_runtime.h>

#define EPS 1e-5f

typedef __attribute__((ext_vector_type(8))) __bf16 bf16x8;
typedef __attribute__((ext_vector_type(4))) float f32x4;

__device__ __forceinline__ float silu_f(float v) {
  return v / (1.f + __expf(-v));
}

// ---------------- prep: fold BN + scales ----------------
__global__ __launch_bounds__(256) void prep_kernel(
    const float* __restrict__ w_experts, const float* __restrict__ bn_gamma,
    const float* __restrict__ bn_beta, const float* __restrict__ bn_mean,
    const float* __restrict__ bn_var, const float* __restrict__ scales,
    const float* __restrict__ w_out, const float* __restrict__ out_gamma,
    const float* __restrict__ out_beta, const float* __restrict__ out_mean,
    const float* __restrict__ out_var,
    float* __restrict__ eff_kernel, float* __restrict__ eff_bias,
    __bf16* __restrict__ w_eff, float* __restrict__ bias2)
{
  const int t = threadIdx.x;
  if (blockIdx.x == 0) {
    const int c = t;
    float k9[9];
#pragma unroll
    for (int r = 0; r < 9; ++r) k9[r] = 0.f;
    float bias = 0.f;
    for (int e = 0; e < 9; ++e) {
      const int ec = e * 256 + c;
      const float tt = bn_gamma[ec] * rsqrtf(bn_var[ec] + EPS);
      const float sc = scales[ec];
      const float es = tt * sc;
      bias += (bn_beta[ec] - bn_mean[ec] * tt) * sc;
      const float* wp = w_experts + (size_t)ec * 9;
#pragma unroll
      for (int r = 0; r < 9; ++r) k9[r] += es * wp[r];
    }
#pragma unroll
    for (int r = 0; r < 9; ++r) eff_kernel[c * 9 + r] = k9[r];
    eff_bias[c] = bias;
    const float t2 = out_gamma[c] * rsqrtf(out_var[c] + EPS);
    bias2[c] = out_beta[c] - out_mean[c] * t2;
  } else {
    const int i = (blockIdx.x - 1) * 256 + t;   // 0..65535
    const int o = i >> 8;
    const float t2 = out_gamma[o] * rsqrtf(out_var[o] + EPS);
    w_eff[i] = (__bf16)(w_out[i] * t2);
  }
}

// ---------------- fused: depthwise 3x3 + SiLU -> LDS -> MFMA out-proj -------
// One block per (b,h) image row. b = blockIdx&7 so XCD k (dispatch id%8) owns
// batch k: 4.2 MB x-slice per XCD L2, stencil rows shared by neighbor blocks.
__global__ __launch_bounds__(256) void fused_kernel(
    const float* __restrict__ x, const float* __restrict__ eff_kernel,
    const float* __restrict__ eff_bias, const __bf16* __restrict__ w_eff,
    const float* __restrict__ bias2, float* __restrict__ out)
{
  __shared__ __align__(16) __bf16 B_lds[64 * 264];  // [pixel][ch], pad 264
  __shared__ float kern_s[256 * 9];
  __shared__ float bias_s[256];
  const int t = threadIdx.x;
  const int id = blockIdx.x;
  const int b = id & 7;          // XCD-local batch
  const int h = id >> 3;         // 0..63

  for (int i = t; i < 2304; i += 256) kern_s[i] = eff_kernel[i];
  bias_s[t] = eff_bias[t];
  __syncthreads();

  const int lane = t & 63;
  const int wv = t >> 6;
  const int lg = lane >> 4;     // lane group -> channel offset
  const int wq = lane & 15;     // 16 lanes cover the 64-wide row (float4 each)
  const int w4 = wq * 4;
  const bool up_ok = (h > 0), dn_ok = (h < 63);
  const int wave_o = wv * 64;

  for (int cg = 0; cg < 4; ++cg) {
#pragma unroll
    for (int cc4 = 0; cc4 < 4; ++cc4) {
      const int ch = cg * 64 + wv * 16 + cc4 * 4 + lg;    // 0..255
      const float* xc = x + (size_t)(b * 256 + ch) * 4096;

      float4 v0, v1, v2;
      v1 = *(const float4*)(xc + h * 64 + w4);
      if (up_ok) v0 = *(const float4*)(xc + (h - 1) * 64 + w4);
      else       v0 = make_float4(0.f, 0.f, 0.f, 0.f);
      if (dn_ok) v2 = *(const float4*)(xc + (h + 1) * 64 + w4);
      else       v2 = make_float4(0.f, 0.f, 0.f, 0.f);

      float k[9];
#pragma unroll
      for (int j = 0; j < 9; ++j) k[j] = kern_s[ch * 9 + j];
      const float bias = bias_s[ch];

      float rowv[3][6];
      const float4 vv[3] = {v0, v1, v2};
#pragma unroll
      for (int r = 0; r < 3; ++r) {
        float vl = __shfl_up(vv[r].w, 1);
        float vr = __shfl_down(vv[r].x, 1);
        rowv[r][0] = (wq == 0) ? 0.f : vl;    // SAME left edge
        rowv[r][1] = vv[r].x;
        rowv[r][2] = vv[r].y;
        rowv[r][3] = vv[r].z;
        rowv[r][4] = vv[r].w;
        rowv[r][5] = (wq == 15) ? 0.f : vr;   // SAME right edge
      }

#pragma unroll
      for (int j = 0; j < 4; ++j) {
        float s = bias;
#pragma unroll
        for (int r = 0; r < 3; ++r)
          s += k[r * 3] * rowv[r][j] + k[r * 3 + 1] * rowv[r][j + 1] + k[r * 3 + 2] * rowv[r][j + 2];
        B_lds[(w4 + j) * 264 + ch] = (__bf16)silu_f(s);
      }
    }
  }

  // Prefetch kk=0 A fragments (global, independent of LDS) before the barrier
  const int quad = lg, l15 = wq;
  bf16x8 af0[4];
#pragma unroll
  for (int i = 0; i < 4; ++i)
    af0[i] = *(const bf16x8*)&w_eff[(size_t)(wave_o + i * 16 + l15) * 256 + quad * 8];

  __syncthreads();

  // ---- GEMM phase: M=256(o) x N=64(p) x K=256(c), 4 waves of 64(o) x 64(p)
  f32x4 acc[4][4];
#pragma unroll
  for (int i = 0; i < 4; ++i)
#pragma unroll
    for (int j = 0; j < 4; ++j) acc[i][j] = (f32x4){0.f, 0.f, 0.f, 0.f};

#pragma unroll
  for (int kk = 0; kk < 8; ++kk) {            // 8 x K32, no barriers
    bf16x8 af[4], bf[4];
#pragma unroll
    for (int i = 0; i < 4; ++i) {
      if (kk == 0) af[i] = af0[i];
      else af[i] = *(const bf16x8*)&w_eff[(size_t)(wave_o + i * 16 + l15) * 256 + kk * 32 + quad * 8];
    }
#pragma unroll
    for (int j = 0; j < 4; ++j)
      bf[j] = *(const bf16x8*)&B_lds[(j * 16 + l15) * 264 + kk * 32 + quad * 8];
#pragma unroll
    for (int i = 0; i < 4; ++i)
#pragma unroll
      for (int j = 0; j < 4; ++j)
        acc[i][j] = __builtin_amdgcn_mfma_f32_16x16x32_bf16(af[i], bf[j], acc[i][j], 0, 0, 0);
  }

  // epilogue: bias + SiLU, fp32 NCHW stores
  float* outb = out + (size_t)b * 256 * 4096 + h * 64;
#pragma unroll
  for (int i = 0; i < 4; ++i) {
#pragma unroll
    for (int r = 0; r < 4; ++r) {
      const int o = wave_o + i * 16 + quad * 4 + r;
      const float bo = bias2[o];
#pragma unroll
      for (int j = 0; j < 4; ++j) {
        const int p = j * 16 + l15;
        outb[(size_t)o * 4096 + p] = silu_f(acc[i][j][r] + bo);
      }
    }
  }
}

extern "C" void kernel_launch(void* const* d_in, const int* in_sizes, int n_in,
                              void* d_out, int out_size, void* d_ws, size_t ws_size,
                              hipStream_t stream) {
  const float* x         = (const float*)d_in[0];
  const float* w_experts = (const float*)d_in[1];
  const float* bn_gamma  = (const float*)d_in[2];
  const float* bn_beta   = (const float*)d_in[3];
  const float* bn_mean   = (const float*)d_in[4];
  const float* bn_var    = (const float*)d_in[5];
  const float* scales    = (const float*)d_in[6];
  const float* w_out     = (const float*)d_in[7];
  const float* out_gamma = (const float*)d_in[8];
  const float* out_beta  = (const float*)d_in[9];
  const float* out_mean  = (const float*)d_in[10];
  const float* out_var   = (const float*)d_in[11];
  float* out = (float*)d_out;

  char* ws = (char*)d_ws;
  float* eff_kernel = (float*)(ws);             // 9216 B
  float* eff_bias   = (float*)(ws + 9216);      // 1 KiB
  __bf16* w_eff     = (__bf16*)(ws + 10240);    // 128 KiB
  float* bias2      = (float*)(ws + 141312);    // 1 KiB

  hipLaunchKernelGGL(prep_kernel, dim3(257), dim3(256), 0, stream,
                     w_experts, bn_gamma, bn_beta, bn_mean, bn_var, scales,
                     w_out, out_gamma, out_beta, out_mean, out_var,
                     eff_kernel, eff_bias, w_eff, bias2);
  hipLaunchKernelGGL(fused_kernel, dim3(512), dim3(256), 0, stream,
                     x, eff_kernel, eff_bias, w_eff, bias2, out);
}

// Round 5
// 124.535 us; speedup vs baseline: 1.0289x; 1.0289x over previous
//
#include <hip/hip_runtime.h>

#define EPS 1e-5f

typedef __attribute__((ext_vector_type(8))) __bf16 bf16x8;
typedef __attribute__((ext_vector_type(4))) float f32x4;

__device__ __forceinline__ float silu_f(float v) {
  return v / (1.f + __expf(-v));
}

// ---------------- prep: fold BN + scales ----------------
__global__ __launch_bounds__(256) void prep_kernel(
    const float* __restrict__ w_experts, const float* __restrict__ bn_gamma,
    const float* __restrict__ bn_beta, const float* __restrict__ bn_mean,
    const float* __restrict__ bn_var, const float* __restrict__ scales,
    const float* __restrict__ w_out, const float* __restrict__ out_gamma,
    const float* __restrict__ out_beta, const float* __restrict__ out_mean,
    const float* __restrict__ out_var,
    float* __restrict__ eff_kernel, float* __restrict__ eff_bias,
    __bf16* __restrict__ w_eff, float* __restrict__ bias2)
{
  const int t = threadIdx.x;
  if (blockIdx.x == 0) {
    const int c = t;
    float k9[9];
#pragma unroll
    for (int r = 0; r < 9; ++r) k9[r] = 0.f;
    float bias = 0.f;
    for (int e = 0; e < 9; ++e) {
      const int ec = e * 256 + c;
      const float tt = bn_gamma[ec] * rsqrtf(bn_var[ec] + EPS);
      const float sc = scales[ec];
      const float es = tt * sc;
      bias += (bn_beta[ec] - bn_mean[ec] * tt) * sc;
      const float* wp = w_experts + (size_t)ec * 9;
#pragma unroll
      for (int r = 0; r < 9; ++r) k9[r] += es * wp[r];
    }
#pragma unroll
    for (int r = 0; r < 9; ++r) eff_kernel[c * 9 + r] = k9[r];
    eff_bias[c] = bias;
    const float t2 = out_gamma[c] * rsqrtf(out_var[c] + EPS);
    bias2[c] = out_beta[c] - out_mean[c] * t2;
  } else {
    const int i = (blockIdx.x - 1) * 256 + t;   // 0..65535
    const int o = i >> 8;
    const float t2 = out_gamma[o] * rsqrtf(out_var[o] + EPS);
    w_eff[i] = (__bf16)(w_out[i] * t2);
  }
}

// ---------------- fused: depthwise 3x3 + SiLU -> LDS -> MFMA out-proj -------
// 512 blocks x 512 threads (8 waves): 2 blocks/CU * 8 waves = 4 waves/SIMD.
// One block per (b,h) image row; b = blockIdx&7 keeps batch b on one XCD L2.
__global__ __launch_bounds__(512, 4) void fused_kernel(
    const float* __restrict__ x, const float* __restrict__ eff_kernel,
    const float* __restrict__ eff_bias, const __bf16* __restrict__ w_eff,
    const float* __restrict__ bias2, float* __restrict__ out)
{
  __shared__ __align__(16) __bf16 B_lds[64 * 264];  // [pixel][ch], pad 264
  __shared__ float kern_s[256 * 9];
  __shared__ float bias_s[256];
  const int t = threadIdx.x;
  const int id = blockIdx.x;
  const int b = id & 7;          // XCD-local batch
  const int h = id >> 3;         // 0..63

  for (int i = t; i < 2304; i += 512) kern_s[i] = eff_kernel[i];
  if (t < 256) bias_s[t] = eff_bias[t];
  __syncthreads();

  const int lane = t & 63;
  const int wv = t >> 6;        // 0..7
  const int lg = lane >> 4;     // lane group -> channel offset
  const int wq = lane & 15;     // 16 lanes cover the 64-wide row (float4 each)
  const int w4 = wq * 4;
  const bool up_ok = (h > 0), dn_ok = (h < 63);

#pragma unroll
  for (int cg = 0; cg < 2; ++cg) {
#pragma unroll
    for (int cc4 = 0; cc4 < 4; ++cc4) {
      const int ch = cg * 128 + wv * 16 + cc4 * 4 + lg;   // 0..255
      const float* xc = x + (size_t)(b * 256 + ch) * 4096;

      float4 v0, v1, v2;
      v1 = *(const float4*)(xc + h * 64 + w4);
      if (up_ok) v0 = *(const float4*)(xc + (h - 1) * 64 + w4);
      else       v0 = make_float4(0.f, 0.f, 0.f, 0.f);
      if (dn_ok) v2 = *(const float4*)(xc + (h + 1) * 64 + w4);
      else       v2 = make_float4(0.f, 0.f, 0.f, 0.f);

      float k[9];
#pragma unroll
      for (int j = 0; j < 9; ++j) k[j] = kern_s[ch * 9 + j];
      const float bias = bias_s[ch];

      float rowv[3][6];
      const float4 vv[3] = {v0, v1, v2};
#pragma unroll
      for (int r = 0; r < 3; ++r) {
        float vl = __shfl_up(vv[r].w, 1);
        float vr = __shfl_down(vv[r].x, 1);
        rowv[r][0] = (wq == 0) ? 0.f : vl;    // SAME left edge
        rowv[r][1] = vv[r].x;
        rowv[r][2] = vv[r].y;
        rowv[r][3] = vv[r].z;
        rowv[r][4] = vv[r].w;
        rowv[r][5] = (wq == 15) ? 0.f : vr;   // SAME right edge
      }

#pragma unroll
      for (int j = 0; j < 4; ++j) {
        float s = bias;
#pragma unroll
        for (int r = 0; r < 3; ++r)
          s += k[r * 3] * rowv[r][j] + k[r * 3 + 1] * rowv[r][j + 1] + k[r * 3 + 2] * rowv[r][j + 2];
        B_lds[(w4 + j) * 264 + ch] = (__bf16)silu_f(s);
      }
    }
  }
  __syncthreads();

  // ---- GEMM phase: M=256(o) x N=64(p) x K=256(c); 8 waves of 32(o) x 64(p)
  const int quad = lg, l15 = wq;
  const int wave_o = wv * 32;

  f32x4 acc[2][4];
#pragma unroll
  for (int i = 0; i < 2; ++i)
#pragma unroll
    for (int j = 0; j < 4; ++j) acc[i][j] = (f32x4){0.f, 0.f, 0.f, 0.f};

#pragma unroll
  for (int kk = 0; kk < 8; ++kk) {            // 8 x K32, no barriers
    bf16x8 af[2], bf[4];
#pragma unroll
    for (int i = 0; i < 2; ++i)
      af[i] = *(const bf16x8*)&w_eff[(size_t)(wave_o + i * 16 + l15) * 256 + kk * 32 + quad * 8];
#pragma unroll
    for (int j = 0; j < 4; ++j)
      bf[j] = *(const bf16x8*)&B_lds[(j * 16 + l15) * 264 + kk * 32 + quad * 8];
#pragma unroll
    for (int i = 0; i < 2; ++i)
#pragma unroll
      for (int j = 0; j < 4; ++j)
        acc[i][j] = __builtin_amdgcn_mfma_f32_16x16x32_bf16(af[i], bf[j], acc[i][j], 0, 0, 0);
  }

  // epilogue: bias + SiLU, fp32 NCHW stores
  float* outb = out + (size_t)b * 256 * 4096 + h * 64;
#pragma unroll
  for (int i = 0; i < 2; ++i) {
#pragma unroll
    for (int r = 0; r < 4; ++r) {
      const int o = wave_o + i * 16 + quad * 4 + r;
      const float bo = bias2[o];
#pragma unroll
      for (int j = 0; j < 4; ++j) {
        const int p = j * 16 + l15;
        outb[(size_t)o * 4096 + p] = silu_f(acc[i][j][r] + bo);
      }
    }
  }
}

extern "C" void kernel_launch(void* const* d_in, const int* in_sizes, int n_in,
                              void* d_out, int out_size, void* d_ws, size_t ws_size,
                              hipStream_t stream) {
  const float* x         = (const float*)d_in[0];
  const float* w_experts = (const float*)d_in[1];
  const float* bn_gamma  = (const float*)d_in[2];
  const float* bn_beta   = (const float*)d_in[3];
  const float* bn_mean   = (const float*)d_in[4];
  const float* bn_var    = (const float*)d_in[5];
  const float* scales    = (const float*)d_in[6];
  const float* w_out     = (const float*)d_in[7];
  const float* out_gamma = (const float*)d_in[8];
  const float* out_beta  = (const float*)d_in[9];
  const float* out_mean  = (const float*)d_in[10];
  const float* out_var   = (const float*)d_in[11];
  float* out = (float*)d_out;

  char* ws = (char*)d_ws;
  float* eff_kernel = (float*)(ws);             // 9216 B
  float* eff_bias   = (float*)(ws + 9216);      // 1 KiB
  __bf16* w_eff     = (__bf16*)(ws + 10240);    // 128 KiB
  float* bias2      = (float*)(ws + 141312);    // 1 KiB

  hipLaunchKernelGGL(prep_kernel, dim3(257), dim3(256), 0, stream,
                     w_experts, bn_gamma, bn_beta, bn_mean, bn_var, scales,
                     w_out, out_gamma, out_beta, out_mean, out_var,
                     eff_kernel, eff_bias, w_eff, bias2);
  hipLaunchKernelGGL(fused_kernel, dim3(512), dim3(512), 0, stream,
                     x, eff_kernel, eff_bias, w_eff, bias2, out);
}